// Round 4
// baseline (544.581 us; speedup 1.0000x reference)
//
#include <hip/hip_runtime.h>

#define NUSERS 100000
#define NITEMS 50000
#define NV (NUSERS + NITEMS)
#define DIM 64
#define NLAYERS 3
#define SCHUNK 1024                   // elements per scan block
#define NSB ((NV + SCHUNK - 1) / SCHUNK)

// ---------------- combined degree histogram ----------------
__global__ void degree_kernel(const int* __restrict__ tu, const int* __restrict__ ti,
                              int* __restrict__ deg, int E) {
    int stride = gridDim.x * blockDim.x;
    for (int e = blockIdx.x * blockDim.x + threadIdx.x; e < E; e += stride) {
        atomicAdd(&deg[tu[e]], 1);
        atomicAdd(&deg[NUSERS + ti[e]], 1);
    }
}

// ---------------- scan stage 1: per-block partial sums ----------------
__global__ void partial_kernel(const int* __restrict__ deg, int* __restrict__ bsum, int N) {
    __shared__ int sh[256];
    int b = blockIdx.x, t = threadIdx.x;
    int base = b * SCHUNK;
    int sum = 0;
    for (int j = t; j < SCHUNK; j += 256) {
        int i = base + j;
        if (i < N) sum += deg[i];
    }
    sh[t] = sum;
    __syncthreads();
    for (int d = 128; d > 0; d >>= 1) {
        if (t < d) sh[t] += sh[t + d];
        __syncthreads();
    }
    if (t == 0) bsum[b] = sh[0];
}

// ---------------- scan stage 2: exclusive scan of partials (1 block) ----------------
__global__ void scanp_kernel(int* __restrict__ bsum, int NB) {
    __shared__ int sh[256];
    int t = threadIdx.x;
    int v = (t < NB) ? bsum[t] : 0;
    sh[t] = v;
    __syncthreads();
    for (int d = 1; d < 256; d <<= 1) {
        int x = (t >= d) ? sh[t - d] : 0;
        __syncthreads();
        sh[t] += x;
        __syncthreads();
    }
    if (t < NB) bsum[t] = sh[t] - v;   // exclusive
}

// ---------------- scan stage 3: final offsets + cursors + rsd ----------------
__global__ void finalscan_kernel(const int* __restrict__ deg, const int* __restrict__ bsum,
                                 int* __restrict__ off, int* __restrict__ cur,
                                 float* __restrict__ rsd, int N, int total) {
    __shared__ int sh[256];
    int b = blockIdx.x, t = threadIdx.x;
    int i0 = b * SCHUNK + t * 4;
    int v0 = 0, v1 = 0, v2 = 0, v3 = 0;
    if (i0 + 0 < N) v0 = deg[i0 + 0];
    if (i0 + 1 < N) v1 = deg[i0 + 1];
    if (i0 + 2 < N) v2 = deg[i0 + 2];
    if (i0 + 3 < N) v3 = deg[i0 + 3];
    int s = v0 + v1 + v2 + v3;
    sh[t] = s;
    __syncthreads();
    for (int d = 1; d < 256; d <<= 1) {
        int x = (t >= d) ? sh[t - d] : 0;
        __syncthreads();
        sh[t] += x;
        __syncthreads();
    }
    int o = sh[t] - s + bsum[b];
    int ov[4] = {o, o + v0, o + v0 + v1, o + v0 + v1 + v2};
    int dv[4] = {v0, v1, v2, v3};
#pragma unroll
    for (int j = 0; j < 4; ++j) {
        int i = i0 + j;
        if (i < N) {
            off[i] = ov[j];
            cur[i] = ov[j];
            rsd[i] = rsqrtf(fmaxf((float)dv[j], 1.0f));
        }
    }
    if (b == 0 && t == 0) off[N] = total;
}

// ---------------- CSR fill: combined neighbor ids, no weights ----------------
__global__ void fill_kernel(const int* __restrict__ tu, const int* __restrict__ ti,
                            int* __restrict__ cur, int* __restrict__ adj, int E) {
    int stride = gridDim.x * blockDim.x;
    for (int e = blockIdx.x * blockDim.x + threadIdx.x; e < E; e += stride) {
        int u = tu[e];
        int iv = NUSERS + ti[e];
        int pu = atomicAdd(&cur[u], 1);
        adj[pu] = iv;                        // user's list: combined item ids
        int pi = atomicAdd(&cur[iv], 1);
        adj[pi] = u;                         // item's list: user ids
    }
}

// ---------------- init: Y = rsd ⊙ [users_w ; items_w] ----------------
__global__ void init_kernel(const float* __restrict__ users_w, const float* __restrict__ items_w,
                            const float* __restrict__ rsd, float* __restrict__ Y) {
    int t = blockIdx.x * blockDim.x + threadIdx.x;   // one thread per 4 floats
    int n4 = NV * (DIM / 4);
    if (t >= n4) return;
    int v = t >> 4;
    float r = rsd[v];
    const float4* src = (v < NUSERS)
        ? reinterpret_cast<const float4*>(users_w) + t
        : reinterpret_cast<const float4*>(items_w) + (t - NUSERS * (DIM / 4));
    float4 x = *src;
    x.x *= r; x.y *= r; x.z *= r; x.w *= r;
    reinterpret_cast<float4*>(Y)[t] = x;
}

// ---------------- gather-reduce propagation (one wave per vertex) ----------------
// y-space: y' = rsd^2 * sum + beta*y   (users) / rsd^2 * sum (items)
// final  : x' = rsd   * sum + beta*y/rsd (users) / rsd * sum (items)
__global__ void gather_kernel(const float* __restrict__ Y, const int* __restrict__ off,
                              const int* __restrict__ adj, const float* __restrict__ rsd,
                              const float* __restrict__ beta_w,
                              float* __restrict__ dst, int layer, int final_layer) {
    int wid = (blockIdx.x * blockDim.x + threadIdx.x) >> 6;
    int lane = threadIdx.x & 63;
    if (wid >= NV) return;
    int s = off[wid];
    int e = off[wid + 1];
    float a0 = 0.f, a1 = 0.f, a2 = 0.f, a3 = 0.f;
    int k = s;
    int i0, i1, i2, i3;
    if (k + 4 <= e) { i0 = adj[k]; i1 = adj[k + 1]; i2 = adj[k + 2]; i3 = adj[k + 3]; }
    for (; k + 8 <= e; k += 4) {
        // prefetch next group's ids while current rows are in flight
        int j0 = adj[k + 4], j1 = adj[k + 5], j2 = adj[k + 6], j3 = adj[k + 7];
        a0 += Y[(size_t)i0 * DIM + lane];
        a1 += Y[(size_t)i1 * DIM + lane];
        a2 += Y[(size_t)i2 * DIM + lane];
        a3 += Y[(size_t)i3 * DIM + lane];
        i0 = j0; i1 = j1; i2 = j2; i3 = j3;
    }
    if (k + 4 <= e) {
        a0 += Y[(size_t)i0 * DIM + lane];
        a1 += Y[(size_t)i1 * DIM + lane];
        a2 += Y[(size_t)i2 * DIM + lane];
        a3 += Y[(size_t)i3 * DIM + lane];
        k += 4;
    }
    for (; k < e; ++k) {
        a0 += Y[(size_t)adj[k] * DIM + lane];
    }
    float sum = (a0 + a1) + (a2 + a3);
    float r = rsd[wid];
    float res;
    if (!final_layer) {
        res = r * r * sum;
        if (wid < NUSERS) {
            float b = tanhf(beta_w[wid * NLAYERS + layer]);
            res += b * Y[(size_t)wid * DIM + lane];
        }
    } else {
        res = r * sum;
        if (wid < NUSERS) {
            float b = tanhf(beta_w[wid * NLAYERS + layer]);
            res += b * (Y[(size_t)wid * DIM + lane] * (1.0f / r));
        }
    }
    dst[(size_t)wid * DIM + lane] = res;
}

extern "C" void kernel_launch(void* const* d_in, const int* in_sizes, int n_in,
                              void* d_out, int out_size, void* d_ws, size_t ws_size,
                              hipStream_t stream) {
    const float* users_w = (const float*)d_in[0];
    const float* items_w = (const float*)d_in[1];
    const float* beta_w  = (const float*)d_in[2];
    const int*   tu      = (const int*)d_in[3];
    const int*   ti      = (const int*)d_in[4];
    const int    E       = in_sizes[3];
    float*       out     = (float*)d_out;

    // ---- workspace layout ----
    char* ws = (char*)d_ws;
    size_t woff = 0;
    auto take = [&](size_t bytes) {
        char* p = ws + woff;
        woff += (bytes + 1023) & ~(size_t)1023;
        return p;
    };
    int*   deg  = (int*)take((size_t)NV * sizeof(int));
    int*   off  = (int*)take((size_t)(NV + 1) * sizeof(int));
    int*   cur  = (int*)take((size_t)NV * sizeof(int));
    float* rsd  = (float*)take((size_t)NV * sizeof(float));
    int*   bsum = (int*)take((size_t)NSB * sizeof(int));
    int*   adj  = (int*)take((size_t)2 * E * sizeof(int));
    float* Y0   = (float*)take((size_t)NV * DIM * sizeof(float));

    const int blk = 256;

    // ---- CSR construction ----
    hipMemsetAsync(deg, 0, (size_t)NV * sizeof(int), stream);
    degree_kernel<<<2048, blk, 0, stream>>>(tu, ti, deg, E);
    partial_kernel<<<NSB, 256, 0, stream>>>(deg, bsum, NV);
    scanp_kernel<<<1, 256, 0, stream>>>(bsum, NSB);
    finalscan_kernel<<<NSB, 256, 0, stream>>>(deg, bsum, off, cur, rsd, NV, 2 * E);
    fill_kernel<<<2048, blk, 0, stream>>>(tu, ti, cur, adj, E);

    // ---- init y-space table ----
    int n4 = NV * (DIM / 4);
    init_kernel<<<(n4 + blk - 1) / blk, blk, 0, stream>>>(users_w, items_w, rsd, Y0);

    // ---- 3 propagation layers: Y0 -> out -> Y0 -> out ----
    int gblocks = ((size_t)NV * 64 + blk - 1) / blk;

    gather_kernel<<<gblocks, blk, 0, stream>>>(Y0, off, adj, rsd, beta_w, out, 0, 0);
    gather_kernel<<<gblocks, blk, 0, stream>>>(out, off, adj, rsd, beta_w, Y0, 1, 0);
    gather_kernel<<<gblocks, blk, 0, stream>>>(Y0, off, adj, rsd, beta_w, out, 2, 1);
}

// Round 5
// 383.967 us; speedup vs baseline: 1.4183x; 1.4183x over previous
//
#include <hip/hip_runtime.h>

#define NUSERS 100000
#define NITEMS 50000
#define NV (NUSERS + NITEMS)
#define DIM 64
#define NLAYERS 3
#define SCHUNK 1024                   // elements per scan block
#define NSB ((NV + SCHUNK - 1) / SCHUNK)

typedef _Float16 half4v __attribute__((ext_vector_type(4)));

// ---------------- degree histogram + per-edge rank capture ----------------
// atomicAdd's return value IS the edge's slot rank within its bucket.
__global__ void degree_kernel(const int* __restrict__ tu, const int* __restrict__ ti,
                              int* __restrict__ deg, int* __restrict__ ru,
                              int* __restrict__ ri, int E) {
    int e = blockIdx.x * blockDim.x + threadIdx.x;
    if (e >= E) return;
    int u = tu[e];
    int iv = NUSERS + ti[e];
    ru[e] = atomicAdd(&deg[u], 1);
    ri[e] = atomicAdd(&deg[iv], 1);
}

// ---------------- scan stage 1: per-block partial sums ----------------
__global__ void partial_kernel(const int* __restrict__ deg, int* __restrict__ bsum, int N) {
    __shared__ int sh[256];
    int b = blockIdx.x, t = threadIdx.x;
    int base = b * SCHUNK;
    int sum = 0;
    for (int j = t; j < SCHUNK; j += 256) {
        int i = base + j;
        if (i < N) sum += deg[i];
    }
    sh[t] = sum;
    __syncthreads();
    for (int d = 128; d > 0; d >>= 1) {
        if (t < d) sh[t] += sh[t + d];
        __syncthreads();
    }
    if (t == 0) bsum[b] = sh[0];
}

// ---------------- scan stage 2: exclusive scan of partials (1 block) ----------------
__global__ void scanp_kernel(int* __restrict__ bsum, int NB) {
    __shared__ int sh[256];
    int t = threadIdx.x;
    int v = (t < NB) ? bsum[t] : 0;
    sh[t] = v;
    __syncthreads();
    for (int d = 1; d < 256; d <<= 1) {
        int x = (t >= d) ? sh[t - d] : 0;
        __syncthreads();
        sh[t] += x;
        __syncthreads();
    }
    if (t < NB) bsum[t] = sh[t] - v;   // exclusive
}

// ---------------- scan stage 3: final offsets + rsd ----------------
__global__ void finalscan_kernel(const int* __restrict__ deg, const int* __restrict__ bsum,
                                 int* __restrict__ off, float* __restrict__ rsd,
                                 int N, int total) {
    __shared__ int sh[256];
    int b = blockIdx.x, t = threadIdx.x;
    int i0 = b * SCHUNK + t * 4;
    int v0 = 0, v1 = 0, v2 = 0, v3 = 0;
    if (i0 + 0 < N) v0 = deg[i0 + 0];
    if (i0 + 1 < N) v1 = deg[i0 + 1];
    if (i0 + 2 < N) v2 = deg[i0 + 2];
    if (i0 + 3 < N) v3 = deg[i0 + 3];
    int s = v0 + v1 + v2 + v3;
    sh[t] = s;
    __syncthreads();
    for (int d = 1; d < 256; d <<= 1) {
        int x = (t >= d) ? sh[t - d] : 0;
        __syncthreads();
        sh[t] += x;
        __syncthreads();
    }
    int o = sh[t] - s + bsum[b];
    int ov[4] = {o, o + v0, o + v0 + v1, o + v0 + v1 + v2};
    int dv[4] = {v0, v1, v2, v3};
#pragma unroll
    for (int j = 0; j < 4; ++j) {
        int i = i0 + j;
        if (i < N) {
            off[i] = ov[j];
            rsd[i] = rsqrtf(fmaxf((float)dv[j], 1.0f));
        }
    }
    if (b == 0 && t == 0) off[N] = total;
}

// ---------------- CSR fill: rank-addressed, NO atomics ----------------
__global__ void fill_kernel(const int* __restrict__ tu, const int* __restrict__ ti,
                            const int* __restrict__ ru, const int* __restrict__ ri,
                            const int* __restrict__ off, int* __restrict__ adj, int E) {
    int e = blockIdx.x * blockDim.x + threadIdx.x;
    if (e >= E) return;
    int u = tu[e];
    int iv = NUSERS + ti[e];
    adj[off[u] + ru[e]] = iv;            // user's list: combined item ids
    adj[off[iv] + ri[e]] = u;            // item's list: user ids
}

// ---------------- init: Yh = f16( rsd ⊙ [users_w ; items_w] ) ----------------
__global__ void init_kernel(const float* __restrict__ users_w, const float* __restrict__ items_w,
                            const float* __restrict__ rsd, _Float16* __restrict__ Yh) {
    int t = blockIdx.x * blockDim.x + threadIdx.x;   // one thread per 4 floats
    int n4 = NV * (DIM / 4);
    if (t >= n4) return;
    int v = t >> 4;
    float r = rsd[v];
    const float4* src = (v < NUSERS)
        ? reinterpret_cast<const float4*>(users_w) + t
        : reinterpret_cast<const float4*>(items_w) + (t - NUSERS * (DIM / 4));
    float4 x = *src;
    half4v h;
    h.x = (_Float16)(x.x * r);
    h.y = (_Float16)(x.y * r);
    h.z = (_Float16)(x.z * r);
    h.w = (_Float16)(x.w * r);
    reinterpret_cast<half4v*>(Yh)[t] = h;
}

// ---------------- gather-reduce propagation (one wave per vertex) ----------------
// y-space recurrence: y' = rsd^2 * sum + beta*y (users) / rsd^2 * sum (items)
// final layer      : x' = rsd * sum + beta*(y/rsd) (users) / rsd * sum (items)
template <bool FINAL>
__global__ void gather_kernel(const _Float16* __restrict__ Yh, const int* __restrict__ off,
                              const int* __restrict__ adj, const float* __restrict__ rsd,
                              const float* __restrict__ beta_w,
                              void* __restrict__ dst_v, int layer) {
    int wid = (blockIdx.x * blockDim.x + threadIdx.x) >> 6;
    int lane = threadIdx.x & 63;
    if (wid >= NV) return;
    int s = off[wid];
    int e = off[wid + 1];
    float a0 = 0.f, a1 = 0.f, a2 = 0.f, a3 = 0.f;
    int k = s;
    int i0, i1, i2, i3;
    if (k + 4 <= e) { i0 = adj[k]; i1 = adj[k + 1]; i2 = adj[k + 2]; i3 = adj[k + 3]; }
    for (; k + 8 <= e; k += 4) {
        // prefetch next group's ids while current rows are in flight
        int j0 = adj[k + 4], j1 = adj[k + 5], j2 = adj[k + 6], j3 = adj[k + 7];
        a0 += (float)Yh[(size_t)i0 * DIM + lane];
        a1 += (float)Yh[(size_t)i1 * DIM + lane];
        a2 += (float)Yh[(size_t)i2 * DIM + lane];
        a3 += (float)Yh[(size_t)i3 * DIM + lane];
        i0 = j0; i1 = j1; i2 = j2; i3 = j3;
    }
    if (k + 4 <= e) {
        a0 += (float)Yh[(size_t)i0 * DIM + lane];
        a1 += (float)Yh[(size_t)i1 * DIM + lane];
        a2 += (float)Yh[(size_t)i2 * DIM + lane];
        a3 += (float)Yh[(size_t)i3 * DIM + lane];
        k += 4;
    }
    for (; k < e; ++k) {
        a0 += (float)Yh[(size_t)adj[k] * DIM + lane];
    }
    float sum = (a0 + a1) + (a2 + a3);
    float r = rsd[wid];
    if (!FINAL) {
        float res = r * r * sum;
        if (wid < NUSERS) {
            float b = tanhf(beta_w[wid * NLAYERS + layer]);
            res += b * (float)Yh[(size_t)wid * DIM + lane];
        }
        ((_Float16*)dst_v)[(size_t)wid * DIM + lane] = (_Float16)res;
    } else {
        float res = r * sum;
        if (wid < NUSERS) {
            float b = tanhf(beta_w[wid * NLAYERS + layer]);
            res += b * ((float)Yh[(size_t)wid * DIM + lane] * (1.0f / r));
        }
        ((float*)dst_v)[(size_t)wid * DIM + lane] = res;
    }
}

extern "C" void kernel_launch(void* const* d_in, const int* in_sizes, int n_in,
                              void* d_out, int out_size, void* d_ws, size_t ws_size,
                              hipStream_t stream) {
    const float* users_w = (const float*)d_in[0];
    const float* items_w = (const float*)d_in[1];
    const float* beta_w  = (const float*)d_in[2];
    const int*   tu      = (const int*)d_in[3];
    const int*   ti      = (const int*)d_in[4];
    const int    E       = in_sizes[3];
    float*       out     = (float*)d_out;

    // ---- workspace layout ----
    char* ws = (char*)d_ws;
    size_t woff = 0;
    auto take = [&](size_t bytes) {
        char* p = ws + woff;
        woff += (bytes + 1023) & ~(size_t)1023;
        return p;
    };
    int*      deg  = (int*)take((size_t)NV * sizeof(int));
    int*      off  = (int*)take((size_t)(NV + 1) * sizeof(int));
    float*    rsd  = (float*)take((size_t)NV * sizeof(float));
    int*      bsum = (int*)take((size_t)NSB * sizeof(int));
    int*      ru   = (int*)take((size_t)E * sizeof(int));
    int*      ri   = (int*)take((size_t)E * sizeof(int));
    int*      adj  = (int*)take((size_t)2 * E * sizeof(int));
    _Float16* Yh0  = (_Float16*)take((size_t)NV * DIM * sizeof(_Float16));
    _Float16* Yh1  = (_Float16*)take((size_t)NV * DIM * sizeof(_Float16));

    const int blk = 256;
    int eblocks = (E + blk - 1) / blk;

    // ---- CSR construction (rank-based, atomic-free fill) ----
    hipMemsetAsync(deg, 0, (size_t)NV * sizeof(int), stream);
    degree_kernel<<<eblocks, blk, 0, stream>>>(tu, ti, deg, ru, ri, E);
    partial_kernel<<<NSB, 256, 0, stream>>>(deg, bsum, NV);
    scanp_kernel<<<1, 256, 0, stream>>>(bsum, NSB);
    finalscan_kernel<<<NSB, 256, 0, stream>>>(deg, bsum, off, rsd, NV, 2 * E);
    fill_kernel<<<eblocks, blk, 0, stream>>>(tu, ti, ru, ri, off, adj, E);

    // ---- init y-space f16 table ----
    int n4 = NV * (DIM / 4);
    init_kernel<<<(n4 + blk - 1) / blk, blk, 0, stream>>>(users_w, items_w, rsd, Yh0);

    // ---- 3 propagation layers: Yh0 -> Yh1 -> Yh0 -> out(f32) ----
    int gblocks = ((size_t)NV * 64 + blk - 1) / blk;

    gather_kernel<false><<<gblocks, blk, 0, stream>>>(Yh0, off, adj, rsd, beta_w, Yh1, 0);
    gather_kernel<false><<<gblocks, blk, 0, stream>>>(Yh1, off, adj, rsd, beta_w, Yh0, 1);
    gather_kernel<true ><<<gblocks, blk, 0, stream>>>(Yh0, off, adj, rsd, beta_w, out, 2);
}